// Round 1
// baseline (361.545 us; speedup 1.0000x reference)
//
#include <hip/hip_runtime.h>
#include <hip/hip_bf16.h>
#include <stdint.h>

#define SQ 4096
#define DM 1280
#define NH 16
#define HDIM 80
#define N_QKV 3840

typedef __attribute__((ext_vector_type(8))) short short8;
typedef __attribute__((ext_vector_type(4))) float f32x4;

__device__ __forceinline__ unsigned short f2bf(float f) {
  union { float f; unsigned int u; } v; v.f = f;
  unsigned int r = v.u + 0x7FFFu + ((v.u >> 16) & 1u);
  return (unsigned short)(r >> 16);
}
__device__ __forceinline__ float bf2f(unsigned short u) {
  union { unsigned int u; float f; } v; v.u = ((unsigned int)u) << 16;
  return v.f;
}

__global__ __launch_bounds__(256) void cvt_f32_bf16(const float* __restrict__ in,
                                                    unsigned short* __restrict__ out, int n4) {
  int i = blockIdx.x * blockDim.x + threadIdx.x;
  if (i >= n4) return;
  float4 v = reinterpret_cast<const float4*>(in)[i];
  ushort4 o;
  o.x = f2bf(v.x); o.y = f2bf(v.y); o.z = f2bf(v.z); o.w = f2bf(v.w);
  reinterpret_cast<ushort4*>(out)[i] = o;
}

__device__ __forceinline__ void gload_lds16(const void* g, void* l) {
  __builtin_amdgcn_global_load_lds(
      (const __attribute__((address_space(1))) void*)g,
      (__attribute__((address_space(3))) void*)l, 16, 0, 0);
}

// C[M][N] = A[M][K](bf16) * B[N][K]^T(bf16) + bias ; OUT_BF16: bf16 else f32
template <int OUT_BF16>
__global__ __launch_bounds__(256) void gemm_bt(const unsigned short* __restrict__ A,
                                               const unsigned short* __restrict__ B,
                                               const float* __restrict__ bias,
                                               void* __restrict__ C, int M, int N, int K) {
  __shared__ __align__(16) unsigned short As[128 * 32];
  __shared__ __align__(16) unsigned short Bs[128 * 32];
  const int tid = threadIdx.x;
  const int wave = tid >> 6, lane = tid & 63;
  const int r15 = lane & 15, kg = lane >> 4;
  const int wr = wave >> 1, wc = wave & 1;
  const int tm = blockIdx.y * 128, tn = blockIdx.x * 128;

  f32x4 acc[4][4];
#pragma unroll
  for (int i = 0; i < 4; ++i)
#pragma unroll
    for (int j = 0; j < 4; ++j) acc[i][j] = {0.f, 0.f, 0.f, 0.f};

  for (int kt = 0; kt < K; kt += 32) {
    __syncthreads();
#pragma unroll
    for (int j = 0; j < 2; ++j) {
      int slot = wave * 64 + lane + j * 256;     // 512 slots of 16B per tile
      int row = slot >> 2, k8 = (slot & 3) << 3;
      gload_lds16(A + (size_t)(tm + row) * K + kt + k8, &As[(wave * 64 + j * 256) * 8]);
      gload_lds16(B + (size_t)(tn + row) * K + kt + k8, &Bs[(wave * 64 + j * 256) * 8]);
    }
    __syncthreads();
    short8 af[4], bfr[4];
#pragma unroll
    for (int mi = 0; mi < 4; ++mi)
      af[mi] = *reinterpret_cast<const short8*>(&As[(wr * 64 + mi * 16 + r15) * 32 + kg * 8]);
#pragma unroll
    for (int ni = 0; ni < 4; ++ni)
      bfr[ni] = *reinterpret_cast<const short8*>(&Bs[(wc * 64 + ni * 16 + r15) * 32 + kg * 8]);
#pragma unroll
    for (int mi = 0; mi < 4; ++mi)
#pragma unroll
      for (int ni = 0; ni < 4; ++ni)
        acc[mi][ni] = __builtin_amdgcn_mfma_f32_16x16x32_bf16(af[mi], bfr[ni], acc[mi][ni], 0, 0, 0);
  }
#pragma unroll
  for (int mi = 0; mi < 4; ++mi) {
#pragma unroll
    for (int ni = 0; ni < 4; ++ni) {
      int col = tn + wc * 64 + ni * 16 + r15;
      float bv = bias[col];
#pragma unroll
      for (int r = 0; r < 4; ++r) {
        int row = tm + wr * 64 + mi * 16 + kg * 4 + r;
        float v = acc[mi][ni][r] + bv;
        if (OUT_BF16)
          ((unsigned short*)C)[(size_t)row * N + col] = f2bf(v);
        else
          ((float*)C)[(size_t)row * N + col] = v;
      }
    }
  }
}

// In-place RoPE on q,k columns of qkv[s][3840]; transpose v into Vt[h][d][s]
__global__ __launch_bounds__(256) void rope_v_kernel(unsigned short* __restrict__ qkv,
                                                     const float* __restrict__ cosb,
                                                     const float* __restrict__ sinb,
                                                     unsigned short* __restrict__ Vt) {
  int h = blockIdx.y, s0 = blockIdx.x * 64;
  __shared__ unsigned short vt[64][80];
  for (int e = threadIdx.x; e < 64 * 40; e += 256) {
    int sl = e / 40, dp = e % 40;
    int s = s0 + sl;
    float c = cosb[s * HDIM + dp];
    float sn = sinb[s * HDIM + dp];
    size_t qb = (size_t)s * N_QKV + h * HDIM;
    float q1 = bf2f(qkv[qb + dp]), q2 = bf2f(qkv[qb + dp + 40]);
    qkv[qb + dp] = f2bf(q1 * c - q2 * sn);
    qkv[qb + dp + 40] = f2bf(q2 * c + q1 * sn);
    size_t kb = qb + DM;
    float k1 = bf2f(qkv[kb + dp]), k2 = bf2f(qkv[kb + dp + 40]);
    qkv[kb + dp] = f2bf(k1 * c - k2 * sn);
    qkv[kb + dp + 40] = f2bf(k2 * c + k1 * sn);
    size_t vb = qb + 2 * DM;
    vt[sl][dp] = qkv[vb + dp];
    vt[sl][dp + 40] = qkv[vb + dp + 40];
  }
  __syncthreads();
  for (int e = threadIdx.x; e < HDIM * 64; e += 256) {
    int d = e >> 6, sl = e & 63;
    Vt[((size_t)h * HDIM + d) * SQ + s0 + sl] = vt[sl][d];
  }
}

// Flash attention with block-diagonal (varlen segment) mask.
// grid (S/64, H); 4 waves, each owns 16 q-rows.
__global__ __launch_bounds__(256) void attn_kernel(const unsigned short* __restrict__ qkv,
                                                   const unsigned short* __restrict__ Vt,
                                                   const int* __restrict__ cu, int nseg,
                                                   unsigned short* __restrict__ attn_out) {
  int h = blockIdx.y, qt = blockIdx.x;
  int tid = threadIdx.x;
  int wave = tid >> 6, lane = tid & 63;
  int r15 = lane & 15, kg = lane >> 4;

  __shared__ int cus[32];
  if (tid <= nseg) cus[tid] = cu[tid];
  __syncthreads();

  auto seg_of = [&](int pos) {
    int s2 = 0;
    for (int i2 = 1; i2 < nseg; ++i2)
      if (pos >= cus[i2]) s2 = i2;
    return s2;
  };

  int key_begin = cus[seg_of(qt * 64)];
  int key_end = cus[seg_of(qt * 64 + 63) + 1];
  int rbase = qt * 64 + wave * 16 + kg * 4;
  int rs[4], re[4];
#pragma unroll
  for (int r = 0; r < 4; ++r) {
    int sg = seg_of(rbase + r);
    rs[r] = cus[sg];
    re[r] = cus[sg + 1];
  }

  // Q A-frags: row = lane&15, k(d) = kg*8+i within 32-slice; zero-pad d>=80
  int qrow = qt * 64 + wave * 16 + r15;
  const unsigned short* qp = qkv + (size_t)qrow * N_QKV + h * HDIM;
  const short8 z8 = {0, 0, 0, 0, 0, 0, 0, 0};
  short8 qf[3];
#pragma unroll
  for (int ds = 0; ds < 3; ++ds) {
    int d0 = ds * 32 + kg * 8;
    qf[ds] = (d0 < HDIM) ? *reinterpret_cast<const short8*>(qp + d0) : z8;
  }

  float m[4] = {-1e30f, -1e30f, -1e30f, -1e30f};
  float l[4] = {0.f, 0.f, 0.f, 0.f};
  f32x4 acc[5];
#pragma unroll
  for (int dg = 0; dg < 5; ++dg) acc[dg] = {0.f, 0.f, 0.f, 0.f};

  __shared__ __align__(16) unsigned short plds[4][16][32];
  const float scale = 0.1118033988749895f;  // 1/sqrt(80)

  for (int k0 = (key_begin & ~31); k0 < key_end; k0 += 32) {
    // S = Q K^T for 16 rows x 32 keys (two 16-key groups)
    f32x4 sa[2];
    sa[0] = {0.f, 0.f, 0.f, 0.f};
    sa[1] = {0.f, 0.f, 0.f, 0.f};
#pragma unroll
    for (int g = 0; g < 2; ++g) {
      int key = k0 + g * 16 + r15;
      int keyc = key < SQ ? key : SQ - 1;
      const unsigned short* kp = qkv + (size_t)keyc * N_QKV + DM + h * HDIM;
#pragma unroll
      for (int ds = 0; ds < 3; ++ds) {
        int d0 = ds * 32 + kg * 8;
        short8 kf = (d0 < HDIM) ? *reinterpret_cast<const short8*>(kp + d0) : z8;
        sa[g] = __builtin_amdgcn_mfma_f32_16x16x32_bf16(qf[ds], kf, sa[g], 0, 0, 0);
      }
    }
    // masked online softmax; rows live at reg r for this lane's kg group
    float p0[4], p1[4], corr[4];
    int key0 = k0 + r15, key1 = k0 + 16 + r15;
#pragma unroll
    for (int r = 0; r < 4; ++r) {
      float v0 = (key0 >= rs[r] && key0 < re[r]) ? sa[0][r] * scale : -1e30f;
      float v1 = (key1 >= rs[r] && key1 < re[r]) ? sa[1][r] * scale : -1e30f;
      float mx = fmaxf(v0, v1);
      mx = fmaxf(mx, __shfl_xor(mx, 1));
      mx = fmaxf(mx, __shfl_xor(mx, 2));
      mx = fmaxf(mx, __shfl_xor(mx, 4));
      mx = fmaxf(mx, __shfl_xor(mx, 8));
      float mn = fmaxf(m[r], mx);
      float c = __expf(m[r] - mn);
      float e0 = __expf(v0 - mn), e1 = __expf(v1 - mn);
      float sm = e0 + e1;
      sm += __shfl_xor(sm, 1);
      sm += __shfl_xor(sm, 2);
      sm += __shfl_xor(sm, 4);
      sm += __shfl_xor(sm, 8);
      l[r] = l[r] * c + sm;
      m[r] = mn;
      corr[r] = c;
      p0[r] = e0;
      p1[r] = e1;
    }
#pragma unroll
    for (int dg = 0; dg < 5; ++dg) {
      f32x4 t = acc[dg];
      t[0] *= corr[0]; t[1] *= corr[1]; t[2] *= corr[2]; t[3] *= corr[3];
      acc[dg] = t;
    }
    // re-layout P (D-frag) -> A-frag via wave-private LDS
#pragma unroll
    for (int r = 0; r < 4; ++r) {
      plds[wave][kg * 4 + r][r15] = f2bf(p0[r]);
      plds[wave][kg * 4 + r][16 + r15] = f2bf(p1[r]);
    }
    asm volatile("s_waitcnt lgkmcnt(0)" ::: "memory");
    short8 pf = *reinterpret_cast<const short8*>(&plds[wave][r15][kg * 8]);
    // PV: B-frag from Vt[h][d][s] (8 consecutive keys)
    int kk = k0 + kg * 8;
    if (kk > SQ - 8) kk = SQ - 8;
#pragma unroll
    for (int dg = 0; dg < 5; ++dg) {
      const unsigned short* vp = Vt + ((size_t)h * HDIM + dg * 16 + r15) * SQ + kk;
      short8 vf = *reinterpret_cast<const short8*>(vp);
      acc[dg] = __builtin_amdgcn_mfma_f32_16x16x32_bf16(pf, vf, acc[dg], 0, 0, 0);
    }
  }
  // epilogue: out[row][h*80 + dg*16 + r15]
#pragma unroll
  for (int r = 0; r < 4; ++r) {
    int row = rbase + r;
    float inv = 1.0f / l[r];
#pragma unroll
    for (int dg = 0; dg < 5; ++dg)
      attn_out[(size_t)row * DM + h * HDIM + dg * 16 + r15] = f2bf(acc[dg][r] * inv);
  }
}

extern "C" void kernel_launch(void* const* d_in, const int* in_sizes, int n_in,
                              void* d_out, int out_size, void* d_ws, size_t ws_size,
                              hipStream_t stream) {
  const float* hidden = (const float*)d_in[0];
  const float* cosb = (const float*)d_in[1];
  const float* sinb = (const float*)d_in[2];
  const float* qkv_w = (const float*)d_in[3];
  const float* qkv_b = (const float*)d_in[4];
  const float* proj_w = (const float*)d_in[5];
  const float* proj_b = (const float*)d_in[6];
  const int* cu = (const int*)d_in[7];
  int nseg = in_sizes[7] - 1;
  float* out = (float*)d_out;

  char* ws = (char*)d_ws;
  unsigned short* Ah = (unsigned short*)(ws);                        // 10,485,760 B
  unsigned short* Wq = (unsigned short*)(ws + 10485760);             //  9,830,400 B
  unsigned short* Wp = (unsigned short*)(ws + 10485760 + 9830400);   //  3,276,800 B
  unsigned short* qkvB = (unsigned short*)(ws + 23592960);           // 31,457,280 B
  unsigned short* Vt = (unsigned short*)(ws + 23592960 + 31457280);  // 10,485,760 B
  unsigned short* attn_out = Ah;  // reuse (Ah dead after GEMM1)

  cvt_f32_bf16<<<dim3((1310720 + 255) / 256), dim3(256), 0, stream>>>(hidden, Ah, 1310720);
  cvt_f32_bf16<<<dim3((1228800 + 255) / 256), dim3(256), 0, stream>>>(qkv_w, Wq, 1228800);
  cvt_f32_bf16<<<dim3((409600 + 255) / 256), dim3(256), 0, stream>>>(proj_w, Wp, 409600);
  gemm_bt<1><<<dim3(30, 32), dim3(256), 0, stream>>>(Ah, Wq, qkv_b, qkvB, SQ, N_QKV, DM);
  rope_v_kernel<<<dim3(64, NH), dim3(256), 0, stream>>>(qkvB, cosb, sinb, Vt);
  attn_kernel<<<dim3(64, NH), dim3(256), 0, stream>>>(qkvB, Vt, cu, nseg, attn_out);
  gemm_bt<0><<<dim3(10, 32), dim3(256), 0, stream>>>(attn_out, Wp, proj_b, out, SQ, DM, DM);
}

// Round 2
// 240.231 us; speedup vs baseline: 1.5050x; 1.5050x over previous
//
#include <hip/hip_runtime.h>
#include <hip/hip_bf16.h>
#include <stdint.h>

#define SQ 4096
#define DM 1280
#define NH 16
#define HDIM 80
#define N_QKV 3840

typedef __attribute__((ext_vector_type(8))) short short8;
typedef __attribute__((ext_vector_type(4))) float f32x4;

__device__ __forceinline__ unsigned short f2bf(float f) {
  union { float f; unsigned int u; } v; v.f = f;
  unsigned int r = v.u + 0x7FFFu + ((v.u >> 16) & 1u);
  return (unsigned short)(r >> 16);
}
__device__ __forceinline__ float bf2f(unsigned short u) {
  union { unsigned int u; float f; } v; v.u = ((unsigned int)u) << 16;
  return v.f;
}

__global__ __launch_bounds__(256) void cvt_f32_bf16(const float* __restrict__ in,
                                                    unsigned short* __restrict__ out, int n4) {
  int i = blockIdx.x * blockDim.x + threadIdx.x;
  if (i >= n4) return;
  float4 v = reinterpret_cast<const float4*>(in)[i];
  ushort4 o;
  o.x = f2bf(v.x); o.y = f2bf(v.y); o.z = f2bf(v.z); o.w = f2bf(v.w);
  reinterpret_cast<ushort4*>(out)[i] = o;
}

__device__ __forceinline__ void gload_lds16(const void* g, void* l) {
  __builtin_amdgcn_global_load_lds(
      (const __attribute__((address_space(1))) void*)g,
      (__attribute__((address_space(3))) void*)l, 16, 0, 0);
}

// C[M][N] = A[M][K](bf16) * B[N][K]^T(bf16) + bias ; OUT_BF16: bf16 else f32
template <int OUT_BF16>
__global__ __launch_bounds__(256) void gemm_bt(const unsigned short* __restrict__ A,
                                               const unsigned short* __restrict__ B,
                                               const float* __restrict__ bias,
                                               void* __restrict__ C, int M, int N, int K) {
  __shared__ __align__(16) unsigned short As[128 * 32];
  __shared__ __align__(16) unsigned short Bs[128 * 32];
  const int tid = threadIdx.x;
  const int wave = tid >> 6, lane = tid & 63;
  const int r15 = lane & 15, kg = lane >> 4;
  const int wr = wave >> 1, wc = wave & 1;
  const int tm = blockIdx.y * 128, tn = blockIdx.x * 128;

  f32x4 acc[4][4];
#pragma unroll
  for (int i = 0; i < 4; ++i)
#pragma unroll
    for (int j = 0; j < 4; ++j) acc[i][j] = {0.f, 0.f, 0.f, 0.f};

  for (int kt = 0; kt < K; kt += 32) {
    __syncthreads();
#pragma unroll
    for (int j = 0; j < 2; ++j) {
      int slot = wave * 64 + lane + j * 256;     // 512 slots of 16B per tile
      int row = slot >> 2, k8 = (slot & 3) << 3;
      gload_lds16(A + (size_t)(tm + row) * K + kt + k8, &As[(wave * 64 + j * 256) * 8]);
      gload_lds16(B + (size_t)(tn + row) * K + kt + k8, &Bs[(wave * 64 + j * 256) * 8]);
    }
    __syncthreads();
    short8 af[4], bfr[4];
#pragma unroll
    for (int mi = 0; mi < 4; ++mi)
      af[mi] = *reinterpret_cast<const short8*>(&As[(wr * 64 + mi * 16 + r15) * 32 + kg * 8]);
#pragma unroll
    for (int ni = 0; ni < 4; ++ni)
      bfr[ni] = *reinterpret_cast<const short8*>(&Bs[(wc * 64 + ni * 16 + r15) * 32 + kg * 8]);
#pragma unroll
    for (int mi = 0; mi < 4; ++mi)
#pragma unroll
      for (int ni = 0; ni < 4; ++ni)
        acc[mi][ni] = __builtin_amdgcn_mfma_f32_16x16x32_bf16(af[mi], bfr[ni], acc[mi][ni], 0, 0, 0);
  }
#pragma unroll
  for (int mi = 0; mi < 4; ++mi) {
#pragma unroll
    for (int ni = 0; ni < 4; ++ni) {
      int col = tn + wc * 64 + ni * 16 + r15;
      float bv = bias[col];
#pragma unroll
      for (int r = 0; r < 4; ++r) {
        int row = tm + wr * 64 + mi * 16 + kg * 4 + r;
        float v = acc[mi][ni][r] + bv;
        if (OUT_BF16)
          ((unsigned short*)C)[(size_t)row * N + col] = f2bf(v);
        else
          ((float*)C)[(size_t)row * N + col] = v;
      }
    }
  }
}

// In-place RoPE on q,k columns of qkv[s][3840]; transpose v into Vt[h][d][s]
__global__ __launch_bounds__(256) void rope_v_kernel(unsigned short* __restrict__ qkv,
                                                     const float* __restrict__ cosb,
                                                     const float* __restrict__ sinb,
                                                     unsigned short* __restrict__ Vt) {
  int h = blockIdx.y, s0 = blockIdx.x * 64;
  __shared__ unsigned short vt[64][80];
  for (int e = threadIdx.x; e < 64 * 40; e += 256) {
    int sl = e / 40, dp = e % 40;
    int s = s0 + sl;
    float c = cosb[s * HDIM + dp];
    float sn = sinb[s * HDIM + dp];
    size_t qb = (size_t)s * N_QKV + h * HDIM;
    float q1 = bf2f(qkv[qb + dp]), q2 = bf2f(qkv[qb + dp + 40]);
    qkv[qb + dp] = f2bf(q1 * c - q2 * sn);
    qkv[qb + dp + 40] = f2bf(q2 * c + q1 * sn);
    size_t kb = qb + DM;
    float k1 = bf2f(qkv[kb + dp]), k2 = bf2f(qkv[kb + dp + 40]);
    qkv[kb + dp] = f2bf(k1 * c - k2 * sn);
    qkv[kb + dp + 40] = f2bf(k2 * c + k1 * sn);
    size_t vb = qb + 2 * DM;
    vt[sl][dp] = qkv[vb + dp];
    vt[sl][dp + 40] = qkv[vb + dp + 40];
  }
  __syncthreads();
  for (int e = threadIdx.x; e < HDIM * 64; e += 256) {
    int d = e >> 6, sl = e & 63;
    Vt[((size_t)h * HDIM + d) * SQ + s0 + sl] = vt[sl][d];
  }
}

// ---- DPP 16-lane row reductions (VALU, no LDS) ----
template <int CTRL>
__device__ __forceinline__ float dpp_f(float x) {
  int xi = __builtin_bit_cast(int, x);
  int r = __builtin_amdgcn_update_dpp(xi, xi, CTRL, 0xf, 0xf, true);
  return __builtin_bit_cast(float, r);
}
__device__ __forceinline__ float rowmax16(float x) {
  x = fmaxf(x, dpp_f<0xB1>(x));    // quad_perm [1,0,3,2]
  x = fmaxf(x, dpp_f<0x4E>(x));    // quad_perm [2,3,0,1]
  x = fmaxf(x, dpp_f<0x141>(x));   // row_half_mirror
  x = fmaxf(x, dpp_f<0x140>(x));   // row_mirror
  return x;
}
__device__ __forceinline__ float rowsum16(float x) {
  x += dpp_f<0xB1>(x);
  x += dpp_f<0x4E>(x);
  x += dpp_f<0x141>(x);
  x += dpp_f<0x140>(x);
  return x;
}

// Flash attention, block-diagonal mask. grid (S/64, H); 4 waves x 16 q-rows.
// KVB=64: K tile reg-staged into LDS [64][88] (176B rows, 2-way banks, b128-aligned).
__global__ __launch_bounds__(256, 3) void attn_kernel(const unsigned short* __restrict__ qkv,
                                                      const unsigned short* __restrict__ Vt,
                                                      const int* __restrict__ cu, int nseg,
                                                      unsigned short* __restrict__ attn_out) {
  constexpr int KROW = 88;   // shorts per K row (80 data + 8 zero pad)
  constexpr int PROW = 68;   // shorts per P row (64 data + 4 pad -> 136B stride)
  __shared__ __align__(16) unsigned short Kl[64 * KROW];
  __shared__ __align__(16) unsigned short Pl[4 * 16 * PROW];
  __shared__ int cus[32];

  const int h = blockIdx.y, qt = blockIdx.x;
  const int tid = threadIdx.x;
  const int wave = tid >> 6, lane = tid & 63;
  const int r15 = lane & 15, kg = lane >> 4;
  const short8 z8 = {0, 0, 0, 0, 0, 0, 0, 0};

  if (tid <= nseg) cus[tid] = cu[tid];
  if (tid < 64) *reinterpret_cast<short8*>(&Kl[tid * KROW + 80]) = z8;  // zero pad once
  __syncthreads();

  auto seg_of = [&](int pos) {
    int s2 = 0;
    for (int i2 = 1; i2 < nseg; ++i2)
      if (pos >= cus[i2]) s2 = i2;
    return s2;
  };

  const int key_begin = cus[seg_of(qt * 64)];
  const int key_end = cus[seg_of(qt * 64 + 63) + 1];
  const int rbase = qt * 64 + wave * 16 + kg * 4;
  int rs[4], re[4];
#pragma unroll
  for (int r = 0; r < 4; ++r) {
    int sg = seg_of(rbase + r);
    rs[r] = cus[sg];
    re[r] = cus[sg + 1];
  }

  // Q A-frags
  const int qrow = qt * 64 + wave * 16 + r15;
  const unsigned short* qp = qkv + (size_t)qrow * N_QKV + h * HDIM;
  short8 qf[3];
#pragma unroll
  for (int ds = 0; ds < 3; ++ds) {
    int d0 = ds * 32 + kg * 8;
    qf[ds] = (d0 < HDIM) ? *reinterpret_cast<const short8*>(qp + d0) : z8;
  }

  float m[4] = {-1e30f, -1e30f, -1e30f, -1e30f};
  float l[4] = {0.f, 0.f, 0.f, 0.f};
  f32x4 acc[5];
#pragma unroll
  for (int dg = 0; dg < 5; ++dg) acc[dg] = {0.f, 0.f, 0.f, 0.f};

  const float scale = 0.1118033988749895f;  // 1/sqrt(80)
  const unsigned short* kbase = qkv + DM + h * HDIM;
  const int kb0 = key_begin & ~63;
  const int nt = (key_end - kb0 + 63) >> 6;

  uint2 st[5];
  auto stage_load = [&](int kb) {
#pragma unroll
    for (int c = 0; c < 5; ++c) {
      int slot = c * 256 + tid;          // 1280 x 8B chunks = 64 rows x 80 shorts
      int key = slot / 20, part = slot % 20;
      st[c] = *reinterpret_cast<const uint2*>(kbase + (size_t)(kb + key) * N_QKV + part * 4);
    }
  };
  auto stage_write = [&]() {
#pragma unroll
    for (int c = 0; c < 5; ++c) {
      int slot = c * 256 + tid;
      int key = slot / 20, part = slot % 20;
      *reinterpret_cast<uint2*>(&Kl[key * KROW + part * 4]) = st[c];
    }
  };

  stage_load(kb0);
  stage_write();
  __syncthreads();

  for (int t = 0; t < nt; ++t) {
    const int k0 = kb0 + (t << 6);
    if (t + 1 < nt) stage_load(k0 + 64);  // async: lands while we compute

    // ---- QK^T: 16 q-rows x 64 keys ----
    f32x4 sa[4];
#pragma unroll
    for (int g = 0; g < 4; ++g) sa[g] = {0.f, 0.f, 0.f, 0.f};
#pragma unroll
    for (int g = 0; g < 4; ++g) {
      const unsigned short* kr = &Kl[(g * 16 + r15) * KROW];
#pragma unroll
      for (int ds = 0; ds < 3; ++ds) {
        int d0 = ds * 32 + kg * 8;
        short8 kf = (d0 < KROW) ? *reinterpret_cast<const short8*>(kr + d0) : z8;
        sa[g] = __builtin_amdgcn_mfma_f32_16x16x32_bf16(qf[ds], kf, sa[g], 0, 0, 0);
      }
    }

    // ---- V frags (issue early; consumed after softmax) ----
    short8 vf[5][2];
#pragma unroll
    for (int dg = 0; dg < 5; ++dg)
#pragma unroll
      for (int g2 = 0; g2 < 2; ++g2)
        vf[dg][g2] = *reinterpret_cast<const short8*>(
            Vt + ((size_t)h * HDIM + dg * 16 + r15) * SQ + k0 + g2 * 32 + kg * 8);

    // ---- masked online softmax (DPP reductions over the 16-lane key axis) ----
    float p[4][4], corr[4];
#pragma unroll
    for (int r = 0; r < 4; ++r) {
      float vv[4];
#pragma unroll
      for (int g = 0; g < 4; ++g) {
        int key = k0 + g * 16 + r15;
        vv[g] = (key >= rs[r] && key < re[r]) ? sa[g][r] * scale : -1e30f;
      }
      float mx = fmaxf(fmaxf(vv[0], vv[1]), fmaxf(vv[2], vv[3]));
      mx = rowmax16(mx);
      float mn = fmaxf(m[r], mx);
      float c = __expf(m[r] - mn);
      float sm = 0.f;
#pragma unroll
      for (int g = 0; g < 4; ++g) {
        p[r][g] = __expf(vv[g] - mn);
        sm += p[r][g];
      }
      sm = rowsum16(sm);
      l[r] = l[r] * c + sm;
      m[r] = mn;
      corr[r] = c;
    }
#pragma unroll
    for (int dg = 0; dg < 5; ++dg) {
      f32x4 t2 = acc[dg];
      t2[0] *= corr[0]; t2[1] *= corr[1]; t2[2] *= corr[2]; t2[3] *= corr[3];
      acc[dg] = t2;
    }

    // ---- P (D-frag) -> A-frag via wave-private LDS ----
    unsigned short* pw = &Pl[wave * 16 * PROW];
#pragma unroll
    for (int r = 0; r < 4; ++r) {
      unsigned short* prow = pw + (kg * 4 + r) * PROW;
#pragma unroll
      for (int g = 0; g < 4; ++g) prow[g * 16 + r15] = f2bf(p[r][g]);
    }
    asm volatile("s_waitcnt lgkmcnt(0)" ::: "memory");
    const unsigned short* prd = pw + r15 * PROW;
    union { short8 v; uint2 d[2]; } pu[2];
#pragma unroll
    for (int g2 = 0; g2 < 2; ++g2) {
      pu[g2].d[0] = *reinterpret_cast<const uint2*>(prd + g2 * 32 + kg * 8);
      pu[g2].d[1] = *reinterpret_cast<const uint2*>(prd + g2 * 32 + kg * 8 + 4);
    }

    // ---- PV ----
#pragma unroll
    for (int dg = 0; dg < 5; ++dg)
#pragma unroll
      for (int g2 = 0; g2 < 2; ++g2)
        acc[dg] = __builtin_amdgcn_mfma_f32_16x16x32_bf16(pu[g2].v, vf[dg][g2], acc[dg], 0, 0, 0);

    __syncthreads();                    // all waves done reading K tile t
    if (t + 1 < nt) stage_write();      // write prefetched tile
    __syncthreads();                    // tile t+1 visible
  }

  // epilogue
#pragma unroll
  for (int r = 0; r < 4; ++r) {
    int row = rbase + r;
    float inv = 1.0f / l[r];
#pragma unroll
    for (int dg = 0; dg < 5; ++dg)
      attn_out[(size_t)row * DM + h * HDIM + dg * 16 + r15] = f2bf(acc[dg][r] * inv);
  }
}

extern "C" void kernel_launch(void* const* d_in, const int* in_sizes, int n_in,
                              void* d_out, int out_size, void* d_ws, size_t ws_size,
                              hipStream_t stream) {
  const float* hidden = (const float*)d_in[0];
  const float* cosb = (const float*)d_in[1];
  const float* sinb = (const float*)d_in[2];
  const float* qkv_w = (const float*)d_in[3];
  const float* qkv_b = (const float*)d_in[4];
  const float* proj_w = (const float*)d_in[5];
  const float* proj_b = (const float*)d_in[6];
  const int* cu = (const int*)d_in[7];
  int nseg = in_sizes[7] - 1;
  float* out = (float*)d_out;

  char* ws = (char*)d_ws;
  unsigned short* Ah = (unsigned short*)(ws);                        // 10,485,760 B
  unsigned short* Wq = (unsigned short*)(ws + 10485760);             //  9,830,400 B
  unsigned short* Wp = (unsigned short*)(ws + 10485760 + 9830400);   //  3,276,800 B
  unsigned short* qkvB = (unsigned short*)(ws + 23592960);           // 31,457,280 B
  unsigned short* Vt = (unsigned short*)(ws + 23592960 + 31457280);  // 10,485,760 B
  unsigned short* attn_out = Ah;  // reuse (Ah dead after GEMM1)

  cvt_f32_bf16<<<dim3((1310720 + 255) / 256), dim3(256), 0, stream>>>(hidden, Ah, 1310720);
  cvt_f32_bf16<<<dim3((1228800 + 255) / 256), dim3(256), 0, stream>>>(qkv_w, Wq, 1228800);
  cvt_f32_bf16<<<dim3((409600 + 255) / 256), dim3(256), 0, stream>>>(proj_w, Wp, 409600);
  gemm_bt<1><<<dim3(30, 32), dim3(256), 0, stream>>>(Ah, Wq, qkv_b, qkvB, SQ, N_QKV, DM);
  rope_v_kernel<<<dim3(64, NH), dim3(256), 0, stream>>>(qkvB, cosb, sinb, Vt);
  attn_kernel<<<dim3(64, NH), dim3(256), 0, stream>>>(qkvB, Vt, cu, nseg, attn_out);
  gemm_bt<0><<<dim3(10, 32), dim3(256), 0, stream>>>(attn_out, Wp, proj_b, out, SQ, DM, DM);
}